// Round 8
// baseline (150.174 us; speedup 1.0000x reference)
//
#include <hip/hip_runtime.h>
#include <hip/hip_bf16.h>
#include <math.h>

#define S_LEN 1024
#define BATCH 4
#define HID 1024
#define NHEADS 16
#define DHEAD 64
#define NTOT 64
#define M_ROWS 4096

typedef unsigned short u16;
typedef unsigned int u32;
typedef __bf16 bf16x8 __attribute__((ext_vector_type(8)));
typedef float f32x4 __attribute__((ext_vector_type(4)));

__device__ __forceinline__ u16 f2bf(float x) {
    __hip_bfloat16 h = __float2bfloat16(x);
    return *(u16*)&h;
}

__device__ __forceinline__ float fexp2(float x) {
#if __has_builtin(__builtin_amdgcn_exp2f)
    return __builtin_amdgcn_exp2f(x);
#else
    return __expf(x * 0.6931471805599453f);
#endif
}

// pack two f32 -> one u32 of 2x bf16 (RNE), gfx950 v_cvt_pk_bf16_f32
__device__ __forceinline__ u32 cvtpk(float a, float b) {
    u32 r;
    asm("v_cvt_pk_bf16_f32 %0, %1, %2" : "=v"(r) : "v"(a), "v"(b));
    return r;
}

// swap lanes 16-31 of a with lanes 0-15 of b (and 48-63 with 32-47)
__device__ __forceinline__ void pl16swap(u32& a, u32& b) {
    asm("v_permlane16_swap_b32 %0, %1" : "+v"(a), "+v"(b));
}

// async global->LDS, 16B/lane; LDS dest = wave-uniform base + lane*16
__device__ __forceinline__ void gll16(const u16* g, u16* l) {
    __builtin_amdgcn_global_load_lds(
        (const __attribute__((address_space(1))) u32*)g,
        (__attribute__((address_space(3))) u32*)l, 16, 0, 0);
}

// ---------------------------------------------------------------------------
// fused fp32 -> bf16 convert for X and the three W matrices
// ---------------------------------------------------------------------------
__global__ __launch_bounds__(256) void cvt_all(
    const float* __restrict__ X, const float* __restrict__ wq,
    const float* __restrict__ wk, const float* __restrict__ wv,
    u16* __restrict__ Xb, u16* __restrict__ Wb)
{
    const int bid = blockIdx.x;
    const float* src;
    u16* dst;
    size_t off;
    if (bid < 4096) {            // X: 4M elems
        src = X; dst = Xb; off = (size_t)bid * 1024;
    } else {                     // W: 3 x 1M elems
        const int wb = bid - 4096;
        const int which = wb >> 10;
        src = (which == 0) ? wq : (which == 1) ? wk : wv;
        dst = Wb + (size_t)which * HID * HID;
        off = (size_t)(wb & 1023) * 1024;
    }
    const size_t idx = off + threadIdx.x * 4;
    float4 x = *(const float4*)(src + idx);
    *(ushort4*)(dst + idx) = make_ushort4(f2bf(x.x), f2bf(x.y), f2bf(x.z), f2bf(x.w));
}

// ---------------------------------------------------------------------------
// QKV projection v3: 128x128 tile, BK=32 DOUBLE-BUFFERED.  Same 32 KB LDS
// footprint as the BK=64 single-buffer (3 blocks/CU preserved — R6 showed
// 2/CU regresses), but the staging drain is now always covered by the
// block's own compute: issue S(t+1) -> 16 MFMA on S(t) -> one barrier.
// The old structure exposed a stage->barrier drain with ZERO compute cover
// every K-step (m233-class stall).
// [128][32] tile swizzle: LDS[row][slot] holds chunk slot^((row>>1)&3);
// read slot = quad^((l15>>1)&3) -> 8 words/bank (b128 floor, conflict-free);
// staging source pre-permuted (linear gll16 dest, rule #21).
// Q,K -> [n][s][d] bf16;  V -> V^T [n][d][s] bf16 directly.
// ---------------------------------------------------------------------------
__global__ __launch_bounds__(256, 3) void qkv_mfma(
    const u16* __restrict__ Xb, const u16* __restrict__ Wb,
    const float* __restrict__ bq, const float* __restrict__ bk,
    const float* __restrict__ bv,
    u16* __restrict__ Qb, u16* __restrict__ Kb, u16* __restrict__ VT)
{
    const int m0 = blockIdx.x * 128;
    const int n0 = blockIdx.y * 128;
    const int which = blockIdx.z;

    __shared__ __align__(16) u16 As[2][128 * 32];   // 2 x 8 KB
    __shared__ __align__(16) u16 Bs[2][128 * 32];   // 2 x 8 KB

    const int tid = threadIdx.x;
    const int lane = tid & 63;
    const int w = tid >> 6;
    const int wm = w & 1, wn = w >> 1;
    const int quad = lane >> 4;
    const int l15 = lane & 15;

    const u16* W = Wb + (size_t)which * HID * HID;

    f32x4 acc[4][4];
    #pragma unroll
    for (int i = 0; i < 4; ++i)
        #pragma unroll
        for (int j = 0; j < 4; ++j)
            #pragma unroll
            for (int r = 0; r < 4; ++r) acc[i][j][r] = 0.0f;

    // staging: seg = 16 rows x 32 u16 (1 KB); lane l: row=l>>2, slot=l&3;
    // logical chunk at slot = slot ^ ((row>>1)&3) -> source col = chunk*8
    const int srow = lane >> 2;                              // 0..15
    const int scol = ((lane & 3) ^ ((lane >> 3) & 3)) * 8;   // u16 units

    // read swizzle: slot = quad ^ ((l15>>1)&3)
    const int xq = (quad ^ ((l15 >> 1) & 3)) * 8;            // u16 units

    // prologue: stage k=0 into buffer 0
    #pragma unroll
    for (int c = 0; c < 2; ++c) {
        const int seg = w * 2 + c;
        const int row = seg * 16 + srow;
        gll16(Xb + (size_t)(m0 + row) * HID + scol, As[0] + seg * 512);
        gll16(W  + (size_t)(n0 + row) * HID + scol, Bs[0] + seg * 512);
    }
    __syncthreads();

    for (int t = 0; t < 32; ++t) {
        const int cur = t & 1;

        if (t < 31) {                        // prefetch next K-step
            const int k1 = (t + 1) * 32;
            #pragma unroll
            for (int c = 0; c < 2; ++c) {
                const int seg = w * 2 + c;
                const int row = seg * 16 + srow;
                gll16(Xb + (size_t)(m0 + row) * HID + k1 + scol,
                      As[cur ^ 1] + seg * 512);
                gll16(W  + (size_t)(n0 + row) * HID + k1 + scol,
                      Bs[cur ^ 1] + seg * 512);
            }
        }

        bf16x8 af[4], bf[4];
        #pragma unroll
        for (int i = 0; i < 4; ++i)
            af[i] = *(const bf16x8*)(As[cur] + (wm * 64 + i * 16 + l15) * 32 + xq);
        #pragma unroll
        for (int j = 0; j < 4; ++j)
            bf[j] = *(const bf16x8*)(Bs[cur] + (wn * 64 + j * 16 + l15) * 32 + xq);
        #pragma unroll
        for (int i = 0; i < 4; ++i)
            #pragma unroll
            for (int j = 0; j < 4; ++j)
                acc[i][j] = __builtin_amdgcn_mfma_f32_16x16x32_bf16(
                    af[i], bf[j], acc[i][j], 0, 0, 0);

        __syncthreads();   // drain (covered by the 16 MFMAs above) + reuse fence
    }

    const float* bias = (which == 0) ? bq : (which == 1) ? bk : bv;
    #pragma unroll
    for (int j = 0; j < 4; ++j) {
        const int o = n0 + wn * 64 + j * 16 + l15;
        const float bias_v = bias[o];
        const int head = o >> 6, d = o & 63;
        #pragma unroll
        for (int i = 0; i < 4; ++i) {
            const int mbase = m0 + wm * 64 + i * 16 + quad * 4;
            const int s = mbase >> 2;
            #pragma unroll
            for (int r = 0; r < 4; ++r) {
                const int n = r * NHEADS + head;
                const u16 hv = f2bf(acc[i][j][r] + bias_v);
                if (which == 0)
                    Qb[((size_t)n * S_LEN + s) * DHEAD + d] = hv;
                else if (which == 1)
                    Kb[((size_t)n * S_LEN + s) * DHEAD + d] = hv;
                else
                    VT[(size_t)n * (DHEAD * S_LEN) + (size_t)d * S_LEN + s] = hv;
            }
        }
    }
}

// ---------------------------------------------------------------------------
// Flash attention (R4 version, the measured best: 143.9 us total).
// Transposed-score, P in registers, KVBLK=128 (2 halves), QBLK=128,
// 512 blocks = exactly 2/CU, reg-P via cvt_pk+permlane16_swap,
// qperm V-offsets, exp2-domain mask in LDS, XCD-chunked swizzle.
// ---------------------------------------------------------------------------
__global__ __launch_bounds__(256, 2) void attn_mfma(
    const u16* __restrict__ Qb, const u16* __restrict__ Kb,
    const u16* __restrict__ VT, const float* __restrict__ mask,
    float* __restrict__ out)
{
    const int bid = blockIdx.x;
    const int swz = (bid & 7) * 64 + (bid >> 3);   // bijective, 512%8==0
    const int n = swz >> 3;
    const int s0 = (swz & 7) * 128;
    const int b = n >> 4, head = n & 15;

    __shared__ __align__(16) char smem[69632];
    u16* Kbuf = (u16*)smem;             // [2 dbuf][2 half][64*64] u16 = 32 KB
    u16* Vbuf = (u16*)(smem + 32768);   // [2 dbuf][2 half][64*64] u16 = 32 KB
    float* Ms = (float*)(smem + 65536); // [1024] f32 = 4 KB (exp2-domain mask)
    float* Of = (float*)smem;           // [128][72] f32 overlay, epilogue

    const int tid = threadIdx.x;
    const int lane = tid & 63;
    const int w = tid >> 6;
    const int quad = lane >> 4;
    const int l15 = lane & 15;
    const int r7 = l15 & 7;
    const size_t nbase = (size_t)n * S_LEN * DHEAD;

    const float LOG2E = 1.44269504f;
    const float SCL2  = 0.18033688f;    // 0.125 * log2(e)
    const float MOFF  = -23.0831099f;   // -16 * log2(e)

    // K-read chunk offsets (chunk = st*4+quad, XOR bank swizzle)
    const int xs0 = ((quad ^ r7) * 8);
    const int xs1 = (((4 + quad) ^ r7) * 8);
    // V-read chunk offsets: chunk = st*4 + perm[quad], perm = [0,2,1,3]
    const int qperm = ((quad & 1) << 1) | (quad >> 1);
    const int xv0 = ((qperm ^ r7) * 8);
    const int xv1 = (((4 + qperm) ^ r7) * 8);

    // staging lane mapping (XOR-permuted global chunk -> swizzled LDS tile)
    const int srow = lane >> 3;
    const int scg  = (lane & 7) ^ (srow & 7);

    // mask row -> LDS, pre-transformed (before first barrier)
    {
        float4 mv = *(const float4*)(mask + (size_t)n * S_LEN + tid * 4);
        Ms[tid * 4 + 0] = fmaf(mv.x, LOG2E, MOFF);
        Ms[tid * 4 + 1] = fmaf(mv.y, LOG2E, MOFF);
        Ms[tid * 4 + 2] = fmaf(mv.z, LOG2E, MOFF);
        Ms[tid * 4 + 3] = fmaf(mv.w, LOG2E, MOFF);
    }

    // Q fragments in registers (MFMA B-operand: Q^T); wave owns 32 q
    bf16x8 qf[2][2];
    #pragma unroll
    for (int mi = 0; mi < 2; ++mi)
        #pragma unroll
        for (int st = 0; st < 2; ++st)
            qf[mi][st] = *(const bf16x8*)(Qb + nbase +
                (size_t)(s0 + w * 32 + mi * 16 + l15) * 64 + st * 32 + quad * 8);

    f32x4 O[2][4];          // O^T[d][q] accumulators
    float l_lane[2];
    #pragma unroll
    for (int mi = 0; mi < 2; ++mi) {
        l_lane[mi] = 0.0f;
        #pragma unroll
        for (int jt = 0; jt < 4; ++jt)
            #pragma unroll
            for (int r = 0; r < 4; ++r) O[mi][jt][r] = 0.0f;
    }

    // prefetch tile 0 (both halves) into dbuf 0
    {
        #pragma unroll
        for (int h = 0; h < 2; ++h) {
            #pragma unroll
            for (int c = 0; c < 2; ++c) {
                const int seg = w * 2 + c;
                const int row = seg * 8 + srow;
                gll16(Kb + nbase + (size_t)(h * 64 + row) * 64 + scg * 8,
                      Kbuf + h * 4096 + seg * 512);
                gll16(VT + nbase + (size_t)row * S_LEN + h * 64 + scg * 8,
                      Vbuf + h * 4096 + seg * 512);
            }
        }
    }
    __syncthreads();

    u32 pw[2][2][2][4];   // [mi][h][st][word], all compile-time indexed

    for (int it = 0; it < 8; ++it) {
        const int t0 = it * 128;
        const u16* kb = Kbuf + (it & 1) * 8192;
        const u16* vb = Vbuf + (it & 1) * 8192;

        if (it < 7) {
            u16* kd = Kbuf + ((it + 1) & 1) * 8192;
            u16* vd = Vbuf + ((it + 1) & 1) * 8192;
            const int t0n = t0 + 128;
            #pragma unroll
            for (int h = 0; h < 2; ++h) {
                #pragma unroll
                for (int c = 0; c < 2; ++c) {
                    const int seg = w * 2 + c;
                    const int row = seg * 8 + srow;
                    gll16(Kb + nbase + (size_t)(t0n + h * 64 + row) * 64 + scg * 8,
                          kd + h * 4096 + seg * 512);
                    gll16(VT + nbase + (size_t)row * S_LEN + t0n + h * 64 + scg * 8,
                          vd + h * 4096 + seg * 512);
                }
            }
        }

        // ---- per half: P^T = K·Q^T, then softmax+pack (short sc lifetime)
        #pragma unroll
        for (int h = 0; h < 2; ++h) {
            const u16* kbh = kb + h * 4096;

            f32x4 sc[2][4];
            #pragma unroll
            for (int mi = 0; mi < 2; ++mi)
                #pragma unroll
                for (int j = 0; j < 4; ++j)
                    #pragma unroll
                    for (int r = 0; r < 4; ++r) sc[mi][j][r] = 0.0f;

            __builtin_amdgcn_s_setprio(1);
            #pragma unroll
            for (int st = 0; st < 2; ++st) {
                const int xo = st ? xs1 : xs0;
                bf16x8 kf[4];
                #pragma unroll
                for (int j = 0; j < 4; ++j)
                    kf[j] = *(const bf16x8*)(kbh + (j * 16 + l15) * 64 + xo);
                #pragma unroll
                for (int mi = 0; mi < 2; ++mi)
                    #pragma unroll
                    for (int j = 0; j < 4; ++j)
                        sc[mi][j] = __builtin_amdgcn_mfma_f32_16x16x32_bf16(
                            kf[j], qf[mi][st], sc[mi][j], 0, 0, 0);
            }
            __builtin_amdgcn_s_setprio(0);

            float4 mb4[4];
            #pragma unroll
            for (int j = 0; j < 4; ++j)
                mb4[j] = *(const float4*)(Ms + t0 + h * 64 + j * 16 + quad * 4);

            #pragma unroll
            for (int mi = 0; mi < 2; ++mi) {
                float pj[4][4];
                #pragma unroll
                for (int j = 0; j < 4; ++j) {
                    pj[j][0] = fexp2(fmaf(sc[mi][j][0], SCL2, mb4[j].x));
                    pj[j][1] = fexp2(fmaf(sc[mi][j][1], SCL2, mb4[j].y));
                    pj[j][2] = fexp2(fmaf(sc[mi][j][2], SCL2, mb4[j].z));
                    pj[j][3] = fexp2(fmaf(sc[mi][j][3], SCL2, mb4[j].w));
                    l_lane[mi] += (pj[j][0] + pj[j][1]) + (pj[j][2] + pj[j][3]);
                }
                u32 W00 = cvtpk(pj[0][0], pj[0][1]), W01 = cvtpk(pj[0][2], pj[0][3]);
                u32 W10 = cvtpk(pj[1][0], pj[1][1]), W11 = cvtpk(pj[1][2], pj[1][3]);
                u32 W20 = cvtpk(pj[2][0], pj[2][1]), W21 = cvtpk(pj[2][2], pj[2][3]);
                u32 W30 = cvtpk(pj[3][0], pj[3][1]), W31 = cvtpk(pj[3][2], pj[3][3]);
                pl16swap(W00, W10); pl16swap(W01, W11);
                pl16swap(W20, W30); pl16swap(W21, W31);
                pw[mi][h][0][0] = W00; pw[mi][h][0][1] = W01;
                pw[mi][h][0][2] = W10; pw[mi][h][0][3] = W11;
                pw[mi][h][1][0] = W20; pw[mi][h][1][1] = W21;
                pw[mi][h][1][2] = W30; pw[mi][h][1][3] = W31;
            }
        }

        // ---- O^T += V^T·P^T over both halves (pf from registers) ----
        __builtin_amdgcn_s_setprio(1);
        #pragma unroll
        for (int h = 0; h < 2; ++h) {
            const u16* vbh = vb + h * 4096;
            #pragma unroll
            for (int st = 0; st < 2; ++st) {
                const int xo = st ? xv1 : xv0;
                bf16x8 vf[4];
                #pragma unroll
                for (int jt = 0; jt < 4; ++jt)
                    vf[jt] = *(const bf16x8*)(vbh + (jt * 16 + l15) * 64 + xo);
                #pragma unroll
                for (int mi = 0; mi < 2; ++mi) {
                    union { u32 wds[4]; bf16x8 v; } pu;
                    pu.wds[0] = pw[mi][h][st][0]; pu.wds[1] = pw[mi][h][st][1];
                    pu.wds[2] = pw[mi][h][st][2]; pu.wds[3] = pw[mi][h][st][3];
                    #pragma unroll
                    for (int jt = 0; jt < 4; ++jt)
                        O[mi][jt] = __builtin_amdgcn_mfma_f32_16x16x32_bf16(
                            vf[jt], pu.v, O[mi][jt], 0, 0, 0);
                }
            }
        }
        __builtin_amdgcn_s_setprio(0);

        __syncthreads();   // buffer reads done; next prefetch may overwrite
    }

    // ---- epilogue ----
    float inv_l[2];
    #pragma unroll
    for (int mi = 0; mi < 2; ++mi) {
        float l = l_lane[mi];
        l += __shfl_xor(l, 16);
        l += __shfl_xor(l, 32);
        inv_l[mi] = 1.0f / l;
    }
    __syncthreads();   // all waves done with Kbuf/Vbuf before overlay

    #pragma unroll
    for (int mi = 0; mi < 2; ++mi) {
        const int q = w * 32 + mi * 16 + l15;
        #pragma unroll
        for (int jt = 0; jt < 4; ++jt)
            #pragma unroll
            for (int r = 0; r < 4; ++r)
                Of[q * 72 + jt * 16 + quad * 4 + r] = O[mi][jt][r] * inv_l[mi];
    }
    __syncthreads();

    const int tx = tid & 15, ty = tid >> 4;
    #pragma unroll
    for (int p = 0; p < 8; ++p) {
        const int q = p * 16 + ty;
        float4 v = *(const float4*)(Of + q * 72 + tx * 4);
        *(float4*)(out + (size_t)(s0 + q) * (BATCH * HID) + (size_t)b * HID +
                   head * DHEAD + tx * 4) = v;
    }
}

extern "C" void kernel_launch(void* const* d_in, const int* in_sizes, int n_in,
                              void* d_out, int out_size, void* d_ws, size_t ws_size,
                              hipStream_t stream)
{
    const float* X    = (const float*)d_in[0];
    const float* mask = (const float*)d_in[1];
    const float* Wq   = (const float*)d_in[2];
    const float* bq   = (const float*)d_in[3];
    const float* Wk   = (const float*)d_in[4];
    const float* bk   = (const float*)d_in[5];
    const float* Wv   = (const float*)d_in[6];
    const float* bv   = (const float*)d_in[7];
    float* out = (float*)d_out;

    const size_t MX = (size_t)M_ROWS * HID;   // 4M elems
    const size_t MW = (size_t)HID * HID;      // 1M elems
    u16* wsp = (u16*)d_ws;
    u16* Xb = wsp;
    u16* Wb = Xb + MX;          // 3 matrices
    u16* Qb = Wb + 3 * MW;
    u16* Kb = Qb + MX;
    u16* VT = Kb + MX;          // total 19M u16 = 38 MB

    cvt_all<<<dim3(4096 + 3072), 256, 0, stream>>>(X, Wq, Wk, Wv, Xb, Wb);
    qkv_mfma<<<dim3(M_ROWS / 128, HID / 128, 3), 256, 0, stream>>>(
        Xb, Wb, bq, bk, bv, Qb, Kb, VT);
    attn_mfma<<<dim3(S_LEN / 128 * NTOT), 256, 0, stream>>>(Qb, Kb, VT, mask, out);
}

// Round 9
// 145.789 us; speedup vs baseline: 1.0301x; 1.0301x over previous
//
#include <hip/hip_runtime.h>
#include <hip/hip_bf16.h>
#include <math.h>

#define S_LEN 1024
#define BATCH 4
#define HID 1024
#define NHEADS 16
#define DHEAD 64
#define NTOT 64
#define M_ROWS 4096

typedef unsigned short u16;
typedef unsigned int u32;
typedef __bf16 bf16x8 __attribute__((ext_vector_type(8)));
typedef float f32x4 __attribute__((ext_vector_type(4)));

__device__ __forceinline__ u16 f2bf(float x) {
    __hip_bfloat16 h = __float2bfloat16(x);
    return *(u16*)&h;
}

__device__ __forceinline__ float fexp2(float x) {
#if __has_builtin(__builtin_amdgcn_exp2f)
    return __builtin_amdgcn_exp2f(x);
#else
    return __expf(x * 0.6931471805599453f);
#endif
}

// pack two f32 -> one u32 of 2x bf16 (RNE), gfx950 v_cvt_pk_bf16_f32
__device__ __forceinline__ u32 cvtpk(float a, float b) {
    u32 r;
    asm("v_cvt_pk_bf16_f32 %0, %1, %2" : "=v"(r) : "v"(a), "v"(b));
    return r;
}

// swap lanes 16-31 of a with lanes 0-15 of b (and 48-63 with 32-47)
__device__ __forceinline__ void pl16swap(u32& a, u32& b) {
    asm("v_permlane16_swap_b32 %0, %1" : "+v"(a), "+v"(b));
}

// async global->LDS, 16B/lane; LDS dest = wave-uniform base + lane*16
__device__ __forceinline__ void gll16(const u16* g, u16* l) {
    __builtin_amdgcn_global_load_lds(
        (const __attribute__((address_space(1))) u32*)g,
        (__attribute__((address_space(3))) u32*)l, 16, 0, 0);
}

// ---------------------------------------------------------------------------
// fused fp32 -> bf16 convert for X and the three W matrices
// ---------------------------------------------------------------------------
__global__ __launch_bounds__(256) void cvt_all(
    const float* __restrict__ X, const float* __restrict__ wq,
    const float* __restrict__ wk, const float* __restrict__ wv,
    u16* __restrict__ Xb, u16* __restrict__ Wb)
{
    const int bid = blockIdx.x;
    const float* src;
    u16* dst;
    size_t off;
    if (bid < 4096) {            // X: 4M elems
        src = X; dst = Xb; off = (size_t)bid * 1024;
    } else {                     // W: 3 x 1M elems
        const int wb = bid - 4096;
        const int which = wb >> 10;
        src = (which == 0) ? wq : (which == 1) ? wk : wv;
        dst = Wb + (size_t)which * HID * HID;
        off = (size_t)(wb & 1023) * 1024;
    }
    const size_t idx = off + threadIdx.x * 4;
    float4 x = *(const float4*)(src + idx);
    *(ushort4*)(dst + idx) = make_ushort4(f2bf(x.x), f2bf(x.y), f2bf(x.z), f2bf(x.w));
}

// ---------------------------------------------------------------------------
// QKV projection (R4 version, reverted verbatim — best measured: BK=32 dbuf
// and BN=192 dbuf both regressed).  128x128 tile, BK=64, single-buffer,
// 3 blocks/CU.  XOR-swizzled LDS via pre-swizzled global_load_lds source.
// Q,K -> [n][s][d] bf16;  V -> V^T [n][d][s] bf16 directly.
// ---------------------------------------------------------------------------
__global__ __launch_bounds__(256, 3) void qkv_mfma(
    const u16* __restrict__ Xb, const u16* __restrict__ Wb,
    const float* __restrict__ bq, const float* __restrict__ bk,
    const float* __restrict__ bv,
    u16* __restrict__ Qb, u16* __restrict__ Kb, u16* __restrict__ VT)
{
    const int m0 = blockIdx.x * 128;
    const int n0 = blockIdx.y * 128;
    const int which = blockIdx.z;

    __shared__ __align__(16) u16 As[128 * 64];   // 16 KB
    __shared__ __align__(16) u16 Bs[128 * 64];   // 16 KB

    const int tid = threadIdx.x;
    const int lane = tid & 63;
    const int w = tid >> 6;
    const int wm = w & 1, wn = w >> 1;
    const int quad = lane >> 4;
    const int l15 = lane & 15;
    const int r7 = l15 & 7;

    const u16* W = Wb + (size_t)which * HID * HID;

    f32x4 acc[4][4];
    #pragma unroll
    for (int i = 0; i < 4; ++i)
        #pragma unroll
        for (int j = 0; j < 4; ++j)
            #pragma unroll
            for (int r = 0; r < 4; ++r) acc[i][j][r] = 0.0f;

    const int srow = lane >> 3;
    const int scg  = ((lane & 7) ^ srow) * 8;    // u16 units

    for (int k0 = 0; k0 < HID; k0 += 64) {
        #pragma unroll
        for (int c = 0; c < 4; ++c) {
            const int seg = w * 4 + c;
            const int row = seg * 8 + srow;
            gll16(Xb + (size_t)(m0 + row) * HID + k0 + scg, As + seg * 512);
            gll16(W  + (size_t)(n0 + row) * HID + k0 + scg, Bs + seg * 512);
        }
        __syncthreads();

        #pragma unroll
        for (int kk = 0; kk < 2; ++kk) {
            const int xo = ((kk * 4 + quad) ^ r7) * 8;   // swizzled 16B slot
            bf16x8 af[4], bf[4];
            #pragma unroll
            for (int i = 0; i < 4; ++i)
                af[i] = *(const bf16x8*)(As + (wm * 64 + i * 16 + l15) * 64 + xo);
            #pragma unroll
            for (int j = 0; j < 4; ++j)
                bf[j] = *(const bf16x8*)(Bs + (wn * 64 + j * 16 + l15) * 64 + xo);
            #pragma unroll
            for (int i = 0; i < 4; ++i)
                #pragma unroll
                for (int j = 0; j < 4; ++j)
                    acc[i][j] = __builtin_amdgcn_mfma_f32_16x16x32_bf16(
                        af[i], bf[j], acc[i][j], 0, 0, 0);
        }
        __syncthreads();
    }

    const float* bias = (which == 0) ? bq : (which == 1) ? bk : bv;
    #pragma unroll
    for (int j = 0; j < 4; ++j) {
        const int o = n0 + wn * 64 + j * 16 + l15;
        const float bias_v = bias[o];
        const int head = o >> 6, d = o & 63;
        #pragma unroll
        for (int i = 0; i < 4; ++i) {
            const int mbase = m0 + wm * 64 + i * 16 + quad * 4;
            const int s = mbase >> 2;
            #pragma unroll
            for (int r = 0; r < 4; ++r) {
                const int n = r * NHEADS + head;
                const u16 hv = f2bf(acc[i][j][r] + bias_v);
                if (which == 0)
                    Qb[((size_t)n * S_LEN + s) * DHEAD + d] = hv;
                else if (which == 1)
                    Kb[((size_t)n * S_LEN + s) * DHEAD + d] = hv;
                else
                    VT[(size_t)n * (DHEAD * S_LEN) + (size_t)d * S_LEN + s] = hv;
            }
        }
    }
}

// ---------------------------------------------------------------------------
// Flash attention, transposed-score, P in registers, KVBLK=128 (2 halves).
// ILP round: both halves' QK^T are issued BACK-TO-BACK (sc[2] live, +32
// VGPR) before any softmax VALU.  In-order wave issue previously stalled
// QK(h1) behind softmax(h0)'s interlock on sc[h0]; now QK(h1) fills the
// MFMA pipe while SM(h0) runs, PV(h0) executes while SM(h1) issues:
//   QK0, QK1 | SM0, PV0 | SM1, PV1   (MFMA covered by other half's VALU)
// All other structure identical to the R4 best (143.9 us): QBLK=128,
// 512 blocks = 2/CU, reg-P via cvt_pk+permlane16_swap, qperm V-offsets,
// exp2-domain mask in LDS, XCD-chunked swizzle.
// ---------------------------------------------------------------------------
__global__ __launch_bounds__(256, 2) void attn_mfma(
    const u16* __restrict__ Qb, const u16* __restrict__ Kb,
    const u16* __restrict__ VT, const float* __restrict__ mask,
    float* __restrict__ out)
{
    const int bid = blockIdx.x;
    const int swz = (bid & 7) * 64 + (bid >> 3);   // bijective, 512%8==0
    const int n = swz >> 3;
    const int s0 = (swz & 7) * 128;
    const int b = n >> 4, head = n & 15;

    __shared__ __align__(16) char smem[69632];
    u16* Kbuf = (u16*)smem;             // [2 dbuf][2 half][64*64] u16 = 32 KB
    u16* Vbuf = (u16*)(smem + 32768);   // [2 dbuf][2 half][64*64] u16 = 32 KB
    float* Ms = (float*)(smem + 65536); // [1024] f32 = 4 KB (exp2-domain mask)
    float* Of = (float*)smem;           // [128][72] f32 overlay, epilogue

    const int tid = threadIdx.x;
    const int lane = tid & 63;
    const int w = tid >> 6;
    const int quad = lane >> 4;
    const int l15 = lane & 15;
    const int r7 = l15 & 7;
    const size_t nbase = (size_t)n * S_LEN * DHEAD;

    const float LOG2E = 1.44269504f;
    const float SCL2  = 0.18033688f;    // 0.125 * log2(e)
    const float MOFF  = -23.0831099f;   // -16 * log2(e)

    // K-read chunk offsets (chunk = st*4+quad, XOR bank swizzle)
    const int xs0 = ((quad ^ r7) * 8);
    const int xs1 = (((4 + quad) ^ r7) * 8);
    // V-read chunk offsets: chunk = st*4 + perm[quad], perm = [0,2,1,3]
    const int qperm = ((quad & 1) << 1) | (quad >> 1);
    const int xv0 = ((qperm ^ r7) * 8);
    const int xv1 = (((4 + qperm) ^ r7) * 8);

    // staging lane mapping (XOR-permuted global chunk -> swizzled LDS tile)
    const int srow = lane >> 3;
    const int scg  = (lane & 7) ^ (srow & 7);

    // mask row -> LDS, pre-transformed (before first barrier)
    {
        float4 mv = *(const float4*)(mask + (size_t)n * S_LEN + tid * 4);
        Ms[tid * 4 + 0] = fmaf(mv.x, LOG2E, MOFF);
        Ms[tid * 4 + 1] = fmaf(mv.y, LOG2E, MOFF);
        Ms[tid * 4 + 2] = fmaf(mv.z, LOG2E, MOFF);
        Ms[tid * 4 + 3] = fmaf(mv.w, LOG2E, MOFF);
    }

    // Q fragments in registers (MFMA B-operand: Q^T); wave owns 32 q
    bf16x8 qf[2][2];
    #pragma unroll
    for (int mi = 0; mi < 2; ++mi)
        #pragma unroll
        for (int st = 0; st < 2; ++st)
            qf[mi][st] = *(const bf16x8*)(Qb + nbase +
                (size_t)(s0 + w * 32 + mi * 16 + l15) * 64 + st * 32 + quad * 8);

    f32x4 O[2][4];          // O^T[d][q] accumulators
    float l_lane[2];
    #pragma unroll
    for (int mi = 0; mi < 2; ++mi) {
        l_lane[mi] = 0.0f;
        #pragma unroll
        for (int jt = 0; jt < 4; ++jt)
            #pragma unroll
            for (int r = 0; r < 4; ++r) O[mi][jt][r] = 0.0f;
    }

    // prefetch tile 0 (both halves) into dbuf 0
    {
        #pragma unroll
        for (int h = 0; h < 2; ++h) {
            #pragma unroll
            for (int c = 0; c < 2; ++c) {
                const int seg = w * 2 + c;
                const int row = seg * 8 + srow;
                gll16(Kb + nbase + (size_t)(h * 64 + row) * 64 + scg * 8,
                      Kbuf + h * 4096 + seg * 512);
                gll16(VT + nbase + (size_t)row * S_LEN + h * 64 + scg * 8,
                      Vbuf + h * 4096 + seg * 512);
            }
        }
    }
    __syncthreads();

    for (int it = 0; it < 8; ++it) {
        const int t0 = it * 128;
        const u16* kb = Kbuf + (it & 1) * 8192;
        const u16* vb = Vbuf + (it & 1) * 8192;

        if (it < 7) {
            u16* kd = Kbuf + ((it + 1) & 1) * 8192;
            u16* vd = Vbuf + ((it + 1) & 1) * 8192;
            const int t0n = t0 + 128;
            #pragma unroll
            for (int h = 0; h < 2; ++h) {
                #pragma unroll
                for (int c = 0; c < 2; ++c) {
                    const int seg = w * 2 + c;
                    const int row = seg * 8 + srow;
                    gll16(Kb + nbase + (size_t)(t0n + h * 64 + row) * 64 + scg * 8,
                          kd + h * 4096 + seg * 512);
                    gll16(VT + nbase + (size_t)row * S_LEN + t0n + h * 64 + scg * 8,
                          vd + h * 4096 + seg * 512);
                }
            }
        }

        // ---- QK^T for BOTH halves back-to-back (no VALU between) ----
        f32x4 sc[2][2][4];   // [h][mi][j]
        #pragma unroll
        for (int h = 0; h < 2; ++h)
            #pragma unroll
            for (int mi = 0; mi < 2; ++mi)
                #pragma unroll
                for (int j = 0; j < 4; ++j)
                    #pragma unroll
                    for (int r = 0; r < 4; ++r) sc[h][mi][j][r] = 0.0f;

        __builtin_amdgcn_s_setprio(1);
        #pragma unroll
        for (int h = 0; h < 2; ++h) {
            const u16* kbh = kb + h * 4096;
            #pragma unroll
            for (int st = 0; st < 2; ++st) {
                const int xo = st ? xs1 : xs0;
                bf16x8 kf[4];
                #pragma unroll
                for (int j = 0; j < 4; ++j)
                    kf[j] = *(const bf16x8*)(kbh + (j * 16 + l15) * 64 + xo);
                #pragma unroll
                for (int mi = 0; mi < 2; ++mi)
                    #pragma unroll
                    for (int j = 0; j < 4; ++j)
                        sc[h][mi][j] = __builtin_amdgcn_mfma_f32_16x16x32_bf16(
                            kf[j], qf[mi][st], sc[h][mi][j], 0, 0, 0);
            }
        }
        __builtin_amdgcn_s_setprio(0);

        // ---- per half: softmax+pack then PV; SM(h1) overlaps PV(h0) ----
        #pragma unroll
        for (int h = 0; h < 2; ++h) {
            float4 mb4[4];
            #pragma unroll
            for (int j = 0; j < 4; ++j)
                mb4[j] = *(const float4*)(Ms + t0 + h * 64 + j * 16 + quad * 4);

            u32 pw[2][2][4];   // [mi][st][word]
            #pragma unroll
            for (int mi = 0; mi < 2; ++mi) {
                float pj[4][4];
                #pragma unroll
                for (int j = 0; j < 4; ++j) {
                    pj[j][0] = fexp2(fmaf(sc[h][mi][j][0], SCL2, mb4[j].x));
                    pj[j][1] = fexp2(fmaf(sc[h][mi][j][1], SCL2, mb4[j].y));
                    pj[j][2] = fexp2(fmaf(sc[h][mi][j][2], SCL2, mb4[j].z));
                    pj[j][3] = fexp2(fmaf(sc[h][mi][j][3], SCL2, mb4[j].w));
                    l_lane[mi] += (pj[j][0] + pj[j][1]) + (pj[j][2] + pj[j][3]);
                }
                u32 W00 = cvtpk(pj[0][0], pj[0][1]), W01 = cvtpk(pj[0][2], pj[0][3]);
                u32 W10 = cvtpk(pj[1][0], pj[1][1]), W11 = cvtpk(pj[1][2], pj[1][3]);
                u32 W20 = cvtpk(pj[2][0], pj[2][1]), W21 = cvtpk(pj[2][2], pj[2][3]);
                u32 W30 = cvtpk(pj[3][0], pj[3][1]), W31 = cvtpk(pj[3][2], pj[3][3]);
                pl16swap(W00, W10); pl16swap(W01, W11);
                pl16swap(W20, W30); pl16swap(W21, W31);
                pw[mi][0][0] = W00; pw[mi][0][1] = W01;
                pw[mi][0][2] = W10; pw[mi][0][3] = W11;
                pw[mi][1][0] = W20; pw[mi][1][1] = W21;
                pw[mi][1][2] = W30; pw[mi][1][3] = W31;
            }

            // ---- O^T += V^T·P^T for this half ----
            const u16* vbh = vb + h * 4096;
            __builtin_amdgcn_s_setprio(1);
            #pragma unroll
            for (int st = 0; st < 2; ++st) {
                const int xo = st ? xv1 : xv0;
                bf16x8 vf[4];
                #pragma unroll
                for (int jt = 0; jt < 4; ++jt)
                    vf[jt] = *(const bf16x8*)(vbh + (jt * 16 + l15) * 64 + xo);
                #pragma unroll
                for (int mi = 0; mi < 2; ++mi) {
                    union { u32 wds[4]; bf16x8 v; } pu;
                    pu.wds[0] = pw[mi][st][0]; pu.wds[1] = pw[mi][st][1];
                    pu.wds[2] = pw[mi][st][2]; pu.wds[3] = pw[mi][st][3];
                    #pragma unroll
                    for (int jt = 0; jt < 4; ++jt)
                        O[mi][jt] = __builtin_amdgcn_mfma_f32_16x16x32_bf16(
                            vf[jt], pu.v, O[mi][jt], 0, 0, 0);
                }
            }
            __builtin_amdgcn_s_setprio(0);
        }

        __syncthreads();   // buffer reads done; next prefetch may overwrite
    }

    // ---- epilogue ----
    float inv_l[2];
    #pragma unroll
    for (int mi = 0; mi < 2; ++mi) {
        float l = l_lane[mi];
        l += __shfl_xor(l, 16);
        l += __shfl_xor(l, 32);
        inv_l[mi] = 1.0f / l;
    }
    __syncthreads();   // all waves done with Kbuf/Vbuf before overlay

    #pragma unroll
    for (int mi = 0; mi < 2; ++mi) {
        const int q = w * 32 + mi * 16 + l15;
        #pragma unroll
        for (int jt = 0; jt < 4; ++jt)
            #pragma unroll
            for (int r = 0; r < 4; ++r)
                Of[q * 72 + jt * 16 + quad * 4 + r] = O[mi][jt][r] * inv_l[mi];
    }
    __syncthreads();

    const int tx = tid & 15, ty = tid >> 4;
    #pragma unroll
    for (int p = 0; p < 8; ++p) {
        const int q = p * 16 + ty;
        float4 v = *(const float4*)(Of + q * 72 + tx * 4);
        *(float4*)(out + (size_t)(s0 + q) * (BATCH * HID) + (size_t)b * HID +
                   head * DHEAD + tx * 4) = v;
    }
}

extern "C" void kernel_launch(void* const* d_in, const int* in_sizes, int n_in,
                              void* d_out, int out_size, void* d_ws, size_t ws_size,
                              hipStream_t stream)
{
    const float* X    = (const float*)d_in[0];
    const float* mask = (const float*)d_in[1];
    const float* Wq   = (const float*)d_in[2];
    const float* bq   = (const float*)d_in[3];
    const float* Wk   = (const float*)d_in[4];
    const float* bk   = (const float*)d_in[5];
    const float* Wv   = (const float*)d_in[6];
    const float* bv   = (const float*)d_in[7];
    float* out = (float*)d_out;

    const size_t MX = (size_t)M_ROWS * HID;   // 4M elems
    const size_t MW = (size_t)HID * HID;      // 1M elems
    u16* wsp = (u16*)d_ws;
    u16* Xb = wsp;
    u16* Wb = Xb + MX;          // 3 matrices
    u16* Qb = Wb + 3 * MW;
    u16* Kb = Qb + MX;
    u16* VT = Kb + MX;          // total 19M u16 = 38 MB

    cvt_all<<<dim3(4096 + 3072), 256, 0, stream>>>(X, Wq, Wk, Wv, Xb, Wb);
    qkv_mfma<<<dim3(M_ROWS / 128, HID / 128, 3), 256, 0, stream>>>(
        Xb, Wb, bq, bk, bv, Qb, Kb, VT);
    attn_mfma<<<dim3(S_LEN / 128 * NTOT), 256, 0, stream>>>(Qb, Kb, VT, mask, out);
}